// Round 5
// baseline (433.941 us; speedup 1.0000x reference)
//
#include <hip/hip_runtime.h>

#define DIM 256
#define NC 12

typedef __attribute__((ext_vector_type(8))) short short8;
typedef __attribute__((ext_vector_type(4))) float f32x4;

__device__ __forceinline__ short f32bf(float f) {
    unsigned u = __builtin_bit_cast(unsigned, f);
    unsigned r = u + 0x7FFFu + ((u >> 16) & 1u);
    return (short)(r >> 16);
}

__device__ __forceinline__ void gld_lds16(const void* g, void* l) {
    __builtin_amdgcn_global_load_lds((const __attribute__((address_space(1))) unsigned int*)g,
                                     (__attribute__((address_space(3))) unsigned int*)l, 16, 0, 0);
}

template<int CTRL>
__device__ __forceinline__ unsigned dppmax(unsigned x) {
    unsigned y = (unsigned)__builtin_amdgcn_update_dpp(0, (int)x, CTRL, 0xF, 0xF, true);
    return x > y ? x : y;
}

// ---------------------------------------------------------------- prep ------
__global__ __launch_bounds__(256) void k_prep(const float* __restrict__ bank,
        const float* __restrict__ W1, const float* __restrict__ W2,
        short* __restrict__ bnbf, double* __restrict__ binv,
        short* __restrict__ w1bf, short* __restrict__ w2bf)
{
    __shared__ double part[4];
    __shared__ double s_inv;
    const int bid = blockIdx.x, t = threadIdx.x;
    if (bid < 1024) {
        const int row = bid;
        if (row < 1000) {
            float v = bank[(size_t)row * DIM + t];
            double ssq = (double)v * (double)v;
            for (int o = 32; o > 0; o >>= 1) ssq += __shfl_down(ssq, o);
            if ((t & 63) == 0) part[t >> 6] = ssq;
            __syncthreads();
            if (t == 0) {
                double s = part[0] + part[1] + part[2] + part[3];
                double n = sqrt(s); if (n < 1e-12) n = 1e-12;
                double inv = 1.0 / n;
                binv[row] = inv; s_inv = inv;
            }
            __syncthreads();
            const int pcol = (((t >> 3) ^ (row & 7)) << 3) | (t & 7);
            bnbf[(size_t)row * DIM + pcol] = f32bf((float)((double)v * s_inv));
        } else {
            bnbf[(size_t)row * DIM + t] = 0;
            if (t == 0) binv[row] = 0.0;
        }
    } else if (bid < 1536) {
        const int i = (bid - 1024) * 256 + t;
        w1bf[i] = f32bf(W1[i]);
    } else {
        const int i = (bid - 1536) * 256 + t;
        w2bf[i] = f32bf(W2[i]);
    }
}

// ---------------------------------------------------------------- sims ------
__global__ __launch_bounds__(256) void k_sims(const float* __restrict__ feat,
        const short* __restrict__ bnbf, short* __restrict__ sims, int qoff)
{
    __shared__ alignas(16) short Qs[64 * 264];
    __shared__ alignas(16) short Ab[64 * 256];
    const int t = threadIdx.x, lane = t & 63, w = t >> 6;
    const int n16 = lane & 15, q4 = lane >> 4;

    {
        const int r = t >> 2, p = t & 3;
        const float4* src = (const float4*)(feat + (size_t)(qoff + blockIdx.x * 64 + r) * DIM + p * 64);
        short* dst = Qs + r * 264 + p * 64;
        #pragma unroll
        for (int i = 0; i < 16; ++i) {
            float4 v = src[i];
            dst[i*4+0] = f32bf(v.x); dst[i*4+1] = f32bf(v.y);
            dst[i*4+2] = f32bf(v.z); dst[i*4+3] = f32bf(v.w);
        }
    }
    const char* gA = (const char*)bnbf;
    char* lA = (char*)Ab;
    #pragma unroll
    for (int i = 0; i < 8; ++i)
        gld_lds16(gA + i * 4096 + t * 16, lA + i * 4096 + (t >> 6) * 1024);
    __syncthreads();

    short8 bq[8][4];
    #pragma unroll
    for (int kc = 0; kc < 8; ++kc)
        #pragma unroll
        for (int nt = 0; nt < 4; ++nt)
            bq[kc][nt] = *(const short8*)(Qs + (nt * 16 + n16) * 264 + kc * 32 + q4 * 8);

    const int ml = w * 16 + n16;
    int aoff[8];
    #pragma unroll
    for (int kc = 0; kc < 8; ++kc)
        aoff[kc] = (ml * 256 + (((kc * 4 + q4) ^ (ml & 7)) << 3)) * 2;

    const f32x4 vzero = {0.f, 0.f, 0.f, 0.f};
    for (int chunk = 0; chunk < 16; ++chunk) {
        f32x4 acc[4];
        acc[0] = vzero; acc[1] = vzero; acc[2] = vzero; acc[3] = vzero;
        #pragma unroll
        for (int kc = 0; kc < 8; ++kc) {
            short8 af = *(const short8*)(lA + aoff[kc]);
            #pragma unroll
            for (int nt = 0; nt < 4; ++nt)
                acc[nt] = __builtin_amdgcn_mfma_f32_16x16x32_bf16(af, bq[kc][nt], acc[nt], 0, 0, 0);
        }
        const int bankb = chunk * 64 + w * 16 + q4 * 4;
        #pragma unroll
        for (int nt = 0; nt < 4; ++nt) {
            const int qc = blockIdx.x * 64 + nt * 16 + n16;
            uint2 u;
            u.x = ((unsigned)(unsigned short)f32bf(acc[nt][0])) |
                  (((unsigned)(unsigned short)f32bf(acc[nt][1])) << 16);
            u.y = ((unsigned)(unsigned short)f32bf(acc[nt][2])) |
                  (((unsigned)(unsigned short)f32bf(acc[nt][3])) << 16);
            *(uint2*)(sims + (size_t)qc * 1024 + bankb) = u;
        }
        __syncthreads();
        if (chunk < 15) {
            #pragma unroll
            for (int i = 0; i < 8; ++i)
                gld_lds16(gA + (size_t)(chunk + 1) * 32768 + i * 4096 + t * 16,
                          lA + i * 4096 + (t >> 6) * 1024);
            __syncthreads();
        }
    }
}

// -------------------------------------------------------------- select ------
__global__ __launch_bounds__(256) void k_select(const short* __restrict__ sims,
        int* __restrict__ top, int qoff)
{
    const int t = threadIdx.x, lane = t & 63, w = t >> 6;
    const int q = blockIdx.x * 4 + w;
    const uint4* p = (const uint4*)(sims + (size_t)q * 1024 + lane * 16);
    uint4 a = p[0], b = p[1];

    unsigned k[16];
    {
        unsigned words[8] = {a.x, a.y, a.z, a.w, b.x, b.y, b.z, b.w};
        #pragma unroll
        for (int j = 0; j < 16; ++j) {
            unsigned h = (j & 1) ? (words[j >> 1] >> 16) : (words[j >> 1] & 0xFFFFu);
            unsigned m = (h ^ 0x8000u) ^ ((0u - (h >> 15)) & 0x7FFFu);
            int idx = lane * 16 + j;
            k[j] = (idx < 1000) ? ((m << 16) | (unsigned)idx) : 0u;
        }
    }
    #pragma unroll
    for (int sz = 2; sz <= 16; sz <<= 1)
        #pragma unroll
        for (int st = sz >> 1; st >= 1; st >>= 1)
            #pragma unroll
            for (int i = 0; i < 16; ++i) {
                int j = i ^ st;
                if (j > i) {
                    bool desc = ((i & sz) == 0);
                    unsigned lo = k[i], hi = k[j];
                    unsigned mx = lo > hi ? lo : hi;
                    unsigned mn = lo > hi ? hi : lo;
                    k[i] = desc ? mx : mn;
                    k[j] = desc ? mn : mx;
                }
            }
    unsigned mine = 0;
    #pragma unroll
    for (int r = 0; r < 12; ++r) {
        unsigned m = k[0];
        m = dppmax<0xB1>(m);
        m = dppmax<0x4E>(m);
        m = dppmax<0x141>(m);
        m = dppmax<0x140>(m);
        m = dppmax<0x142>(m);
        m = dppmax<0x143>(m);
        unsigned wm = (unsigned)__builtin_amdgcn_readlane((int)m, 63);
        if (lane == r) mine = wm;
        if (k[0] == wm) {
            #pragma unroll
            for (int s = 0; s < 12; ++s) k[s] = k[s + 1];
        }
    }
    if (lane < 12) top[(size_t)(qoff + q) * NC + lane] = (int)(mine & 0xFFFFu);
}

// -------------------------------------------------------------- refine ------
// 16 lanes/query, 4 queries/wave. FP32 fast path (worst-case sim error
// <= ~3e-6) with wave-uniform FP64 fallback when the rank4/rank5 gap < 1e-5
// (~1% of queries) -> top-5 membership provably matches fp64 ranking.
// Weighted sum over the 5 selected rows via rank-compacted pointers.
__global__ __launch_bounds__(256) void k_refine(const float* __restrict__ feat,
        const float* __restrict__ bank, const int* __restrict__ top,
        const double* __restrict__ binv, short* __restrict__ nf)
{
    const int t = threadIdx.x, lane = t & 63, w = t >> 6;
    const int g = lane >> 4, u = lane & 15;
    const int q = blockIdx.x * 16 + w * 4 + g;

    int ci[NC];
    #pragma unroll
    for (int c = 0; c < NC; ++c) ci[c] = top[(size_t)q * NC + c];
    double bd[NC];
    #pragma unroll
    for (int c = 0; c < NC; ++c) bd[c] = binv[ci[c]];

    float qf[16];
    float ssf = 0.f;
    #pragma unroll
    for (int j = 0; j < 4; ++j) {
        float4 v = *(const float4*)(feat + (size_t)q * DIM + j * 64 + u * 4);
        qf[j*4+0] = v.x; qf[j*4+1] = v.y; qf[j*4+2] = v.z; qf[j*4+3] = v.w;
        ssf += v.x*v.x + v.y*v.y + v.z*v.z + v.w*v.w;
    }
    #pragma unroll
    for (int o = 1; o < 16; o <<= 1) ssf += __shfl_xor(ssf, o, 16);
    float nq = sqrtf(ssf); if (nq < 1e-12f) nq = 1e-12f;
    const float qi = 1.f / nq;

    // fp32 partial dots (4-way split), butterfly reduce within 16-lane group
    float s[NC];
    #pragma unroll
    for (int c = 0; c < NC; ++c) {
        const float* brow = bank + (size_t)ci[c] * DIM + u * 4;
        float a0 = 0.f, a1 = 0.f, a2 = 0.f, a3 = 0.f;
        #pragma unroll
        for (int j = 0; j < 4; ++j) {
            float4 b = *(const float4*)(brow + j * 64);
            a0 += qf[j*4+0] * b.x; a1 += qf[j*4+1] * b.y;
            a2 += qf[j*4+2] * b.z; a3 += qf[j*4+3] * b.w;
        }
        s[c] = (a0 + a1) + (a2 + a3);
    }
    #pragma unroll
    for (int o = 1; o < 16; o <<= 1)
        #pragma unroll
        for (int c = 0; c < NC; ++c) s[c] += __shfl_xor(s[c], o, 16);

    float vf[NC];
    unsigned long long key[NC];
    #pragma unroll
    for (int c = 0; c < NC; ++c) {
        float v = s[c] * qi * (float)bd[c];
        vf[c] = v;
        unsigned ub = __builtin_bit_cast(unsigned, v);
        unsigned m = (ub >> 31) ? ~ub : (ub | 0x80000000u);
        key[c] = ((unsigned long long)m << 10) | (unsigned long long)(1023 - ci[c]);
    }

    int rank[NC];
    #pragma unroll
    for (int c = 0; c < NC; ++c) rank[c] = 0;
    #pragma unroll
    for (int c1 = 0; c1 < NC; ++c1)
        #pragma unroll
        for (int c2 = c1 + 1; c2 < NC; ++c2) {
            const bool gt = key[c1] > key[c2];
            rank[c2] += gt ? 1 : 0;
            rank[c1] += gt ? 0 : 1;
        }

    // boundary gap check -> rare fp64 fallback (wave-uniform)
    float v5 = 0.f, v6 = 0.f;
    #pragma unroll
    for (int c = 0; c < NC; ++c) {
        v5 += (rank[c] == 4) ? vf[c] : 0.f;
        v6 += (rank[c] == 5) ? vf[c] : 0.f;
    }
    const int need = (v5 - v6) < 1e-5f;
    if (__any(need)) {
        double ssd = 0.0;
        #pragma unroll
        for (int j = 0; j < 16; ++j) ssd += (double)qf[j] * (double)qf[j];
        #pragma unroll
        for (int o = 1; o < 16; o <<= 1) ssd += __shfl_xor(ssd, o, 16);
        double nd = sqrt(ssd); if (nd < 1e-12) nd = 1e-12;
        const double qid = 1.0 / nd;
        double sd[NC];
        #pragma unroll
        for (int c = 0; c < NC; ++c) {
            const float* brow = bank + (size_t)ci[c] * DIM + u * 4;
            double a0 = 0, a1 = 0, a2 = 0, a3 = 0;
            #pragma unroll
            for (int j = 0; j < 4; ++j) {
                float4 b = *(const float4*)(brow + j * 64);
                a0 += (double)qf[j*4+0] * b.x; a1 += (double)qf[j*4+1] * b.y;
                a2 += (double)qf[j*4+2] * b.z; a3 += (double)qf[j*4+3] * b.w;
            }
            sd[c] = (a0 + a1) + (a2 + a3);
        }
        #pragma unroll
        for (int o = 1; o < 16; o <<= 1)
            #pragma unroll
            for (int c = 0; c < NC; ++c) sd[c] += __shfl_xor(sd[c], o, 16);
        #pragma unroll
        for (int c = 0; c < NC; ++c) {
            double vd = sd[c] * qid * bd[c];
            vf[c] = (float)vd;
            unsigned long long ub = __builtin_bit_cast(unsigned long long, vd);
            unsigned long long m = (ub >> 63) ? ~ub : (ub | 0x8000000000000000ULL);
            key[c] = (m & ~0x3FFULL) | (unsigned long long)(1023 - ci[c]);
        }
        #pragma unroll
        for (int c = 0; c < NC; ++c) rank[c] = 0;
        #pragma unroll
        for (int c1 = 0; c1 < NC; ++c1)
            #pragma unroll
            for (int c2 = c1 + 1; c2 < NC; ++c2) {
                const bool gt = key[c1] > key[c2];
                rank[c2] += gt ? 1 : 0;
                rank[c1] += gt ? 0 : 1;
            }
    }

    // softmax over rank<5
    float vm = vf[0];
    #pragma unroll
    for (int c = 1; c < NC; ++c) vm = fmaxf(vm, vf[c]);
    float e[NC]; float wsum = 0.f;
    #pragma unroll
    for (int c = 0; c < NC; ++c) {
        float ex = __expf(vf[c] - vm);
        ex = (rank[c] < 5) ? ex : 0.f;
        e[c] = ex; wsum += ex;
    }
    const float inv = 1.f / wsum;

    // compact the 5 selected (index, weight) pairs
    int   selidx[5];
    float selw[5];
    #pragma unroll
    for (int k = 0; k < 5; ++k) {
        int idx = 0; float wv = 0.f;
        #pragma unroll
        for (int c = 0; c < NC; ++c) {
            const bool is = (rank[c] == k);
            idx += is ? ci[c] : 0;
            wv  += is ? e[c]  : 0.f;
        }
        selidx[k] = idx; selw[k] = wv * inv;
    }

    float4 oa[4];
    #pragma unroll
    for (int j = 0; j < 4; ++j) { oa[j].x = 0.f; oa[j].y = 0.f; oa[j].z = 0.f; oa[j].w = 0.f; }
    #pragma unroll
    for (int k = 0; k < 5; ++k) {
        const float wc = selw[k];
        const float* brow = bank + (size_t)selidx[k] * DIM + u * 4;
        #pragma unroll
        for (int j = 0; j < 4; ++j) {
            float4 b = *(const float4*)(brow + j * 64);
            oa[j].x += wc * b.x; oa[j].y += wc * b.y;
            oa[j].z += wc * b.z; oa[j].w += wc * b.w;
        }
    }
    short* od = nf + (size_t)q * DIM + u * 4;
    #pragma unroll
    for (int j = 0; j < 4; ++j) {
        uint2 pk;
        pk.x = ((unsigned)(unsigned short)f32bf(oa[j].x)) |
               (((unsigned)(unsigned short)f32bf(oa[j].y)) << 16);
        pk.y = ((unsigned)(unsigned short)f32bf(oa[j].z)) |
               (((unsigned)(unsigned short)f32bf(oa[j].w)) << 16);
        *(uint2*)(od + j * 64) = pk;
    }
}

// --------------------------------------------------------------- MLP 1 ------
// h = relu([feat|nf] @ W1^T + b1). Block = 64 rows x all 256 cols (feat/nf
// read ONCE). 4 waves, each 64x64. K=512 in 16 chunks of 32.
__global__ __launch_bounds__(256) void k_mlp1(const float* __restrict__ feat,
        const short* __restrict__ nf, const short* __restrict__ w1bf,
        const float* __restrict__ b1, short* __restrict__ h)
{
    __shared__ alignas(16) short As[64 * 40];
    __shared__ alignas(16) short Bs[256 * 40];
    const int t = threadIdx.x, lane = t & 63, w = t >> 6;
    const int mb = blockIdx.x * 64;
    const int r = t >> 2, p = t & 3;
    const int n16 = lane & 15, ko = (lane >> 4) << 3;
    const f32x4 vzero = {0.f, 0.f, 0.f, 0.f};

    f32x4 acc[4][4];
    #pragma unroll
    for (int a = 0; a < 4; ++a)
        #pragma unroll
        for (int b = 0; b < 4; ++b) acc[a][b] = vzero;

    for (int kc = 0; kc < 16; ++kc) {
        short* ad = As + r * 40 + p * 8;
        if (kc < 8) {
            const float4* s = (const float4*)(feat + (size_t)(mb + r) * 256 + kc * 32 + p * 8);
            float4 v0 = s[0], v1 = s[1];
            ad[0] = f32bf(v0.x); ad[1] = f32bf(v0.y); ad[2] = f32bf(v0.z); ad[3] = f32bf(v0.w);
            ad[4] = f32bf(v1.x); ad[5] = f32bf(v1.y); ad[6] = f32bf(v1.z); ad[7] = f32bf(v1.w);
        } else {
            *(uint4*)ad = *(const uint4*)(nf + (size_t)(mb + r) * 256 + (kc - 8) * 32 + p * 8);
        }
        {
            const uint4* bsrc = (const uint4*)(w1bf + (size_t)t * 512 + kc * 32);
            short* bdst = Bs + t * 40;
            *(uint4*)(bdst +  0) = bsrc[0];
            *(uint4*)(bdst +  8) = bsrc[1];
            *(uint4*)(bdst + 16) = bsrc[2];
            *(uint4*)(bdst + 24) = bsrc[3];
        }
        __syncthreads();
        short8 af[4], bf[4];
        #pragma unroll
        for (int mt = 0; mt < 4; ++mt)
            af[mt] = *(const short8*)(As + (mt * 16 + n16) * 40 + ko);
        #pragma unroll
        for (int nt = 0; nt < 4; ++nt)
            bf[nt] = *(const short8*)(Bs + (w * 64 + nt * 16 + n16) * 40 + ko);
        #pragma unroll
        for (int mt = 0; mt < 4; ++mt)
            #pragma unroll
            for (int nt = 0; nt < 4; ++nt)
                acc[mt][nt] = __builtin_amdgcn_mfma_f32_16x16x32_bf16(af[mt], bf[nt], acc[mt][nt], 0, 0, 0);
        __syncthreads();
    }
    {
        const int rq = (lane >> 4) << 2;
        const int cc = lane & 15;
        #pragma unroll
        for (int mt = 0; mt < 4; ++mt)
            #pragma unroll
            for (int nt = 0; nt < 4; ++nt) {
                const int row = mb + mt * 16 + rq;
                const int col = w * 64 + nt * 16 + cc;
                const float bias = b1[col];
                #pragma unroll
                for (int rr = 0; rr < 4; ++rr) {
                    float v = acc[mt][nt][rr] + bias;
                    v = fmaxf(v, 0.f);
                    h[(size_t)(row + rr) * 256 + col] = f32bf(v);
                }
            }
    }
}

// --------------------------------------------------------------- MLP 2 ------
// out = h @ W2^T + b2. Block = 64 rows x 256 cols (h read once). K=256.
// NOTE round-4 bug fixed here: each thread must stage 32 shorts (4x uint4)
// of its W2 row per K-chunk; staging only 2x uint4 left shorts 16..31
// uninitialized -> NaN.
__global__ __launch_bounds__(256) void k_mlp2(const short* __restrict__ h,
        const short* __restrict__ w2bf, const float* __restrict__ b2,
        float* __restrict__ out)
{
    __shared__ alignas(16) short As[64 * 40];
    __shared__ alignas(16) short Bs[256 * 40];
    const int t = threadIdx.x, lane = t & 63, w = t >> 6;
    const int mb = blockIdx.x * 64;
    const int r = t >> 2, p = t & 3;
    const int n16 = lane & 15, ko = (lane >> 4) << 3;
    const f32x4 vzero = {0.f, 0.f, 0.f, 0.f};

    f32x4 acc[4][4];
    #pragma unroll
    for (int a = 0; a < 4; ++a)
        #pragma unroll
        for (int b = 0; b < 4; ++b) acc[a][b] = vzero;

    for (int kc = 0; kc < 8; ++kc) {
        *(uint4*)(As + r * 40 + p * 8) =
            *(const uint4*)(h + (size_t)(mb + r) * 256 + kc * 32 + p * 8);
        {
            const uint4* bsrc = (const uint4*)(w2bf + (size_t)t * 256 + kc * 32);
            short* bdst = Bs + t * 40;
            *(uint4*)(bdst +  0) = bsrc[0];
            *(uint4*)(bdst +  8) = bsrc[1];
            *(uint4*)(bdst + 16) = bsrc[2];
            *(uint4*)(bdst + 24) = bsrc[3];
        }
        __syncthreads();
        short8 af[4], bf[4];
        #pragma unroll
        for (int mt = 0; mt < 4; ++mt)
            af[mt] = *(const short8*)(As + (mt * 16 + n16) * 40 + ko);
        #pragma unroll
        for (int nt = 0; nt < 4; ++nt)
            bf[nt] = *(const short8*)(Bs + (w * 64 + nt * 16 + n16) * 40 + ko);
        #pragma unroll
        for (int mt = 0; mt < 4; ++mt)
            #pragma unroll
            for (int nt = 0; nt < 4; ++nt)
                acc[mt][nt] = __builtin_amdgcn_mfma_f32_16x16x32_bf16(af[mt], bf[nt], acc[mt][nt], 0, 0, 0);
        __syncthreads();
    }
    {
        const int rq = (lane >> 4) << 2;
        const int cc = lane & 15;
        #pragma unroll
        for (int mt = 0; mt < 4; ++mt)
            #pragma unroll
            for (int nt = 0; nt < 4; ++nt) {
                const int row = mb + mt * 16 + rq;
                const int col = w * 64 + nt * 16 + cc;
                const float bias = b2[col];
                #pragma unroll
                for (int rr = 0; rr < 4; ++rr)
                    out[(size_t)(row + rr) * 256 + col] = acc[mt][nt][rr] + bias;
            }
    }
}

// ------------------------------------------------------------- launcher -----
extern "C" void kernel_launch(void* const* d_in, const int* in_sizes, int n_in,
                              void* d_out, int out_size, void* d_ws, size_t ws_size,
                              hipStream_t stream) {
    const float* feat = (const float*)d_in[0];
    const float* bank = (const float*)d_in[1];
    const float* W1   = (const float*)d_in[2];
    const float* b1   = (const float*)d_in[3];
    const float* W2   = (const float*)d_in[4];
    const float* b2   = (const float*)d_in[5];
    float* out = (float*)d_out;

    char* ws = (char*)d_ws;
    short*  bnbf = (short*)(ws + 0);              // 1024*256*2   = 524288
    double* binv = (double*)(ws + 524288);        // 1024*8       = 8192
    short*  w1bf = (short*)(ws + 532480);         // 131072*2     = 262144
    short*  w2bf = (short*)(ws + 794624);         // 65536*2      = 131072
    int*    top  = (int*)(ws + 925696);           // 65536*12*4   = 3145728
    short*  nf   = (short*)(ws + 4071424);        // 65536*256*2  = 33554432
    short*  X    = (short*)(ws + 37625856);       // 33554432: sims slices, then h
    // total 71180288 bytes

    k_prep<<<1792, 256, 0, stream>>>(bank, W1, W2, bnbf, binv, w1bf, w2bf);
    for (int s = 0; s < 4; ++s) {
        const int qoff = s * 16384;
        k_sims  <<<256,  256, 0, stream>>>(feat, bnbf, X, qoff);
        k_select<<<4096, 256, 0, stream>>>(X, top, qoff);
    }
    k_refine<<<4096, 256, 0, stream>>>(feat, bank, top, binv, nf);
    k_mlp1  <<<1024, 256, 0, stream>>>(feat, nf, w1bf, b1, (short*)X);
    k_mlp2  <<<1024, 256, 0, stream>>>((short*)X, w2bf, b2, out);
}

// Round 7
// 407.549 us; speedup vs baseline: 1.0648x; 1.0648x over previous
//
#include <hip/hip_runtime.h>

#define DIM 256
#define NC 12

typedef __attribute__((ext_vector_type(8))) short short8;
typedef __attribute__((ext_vector_type(4))) float f32x4;

__device__ __forceinline__ short f32bf(float f) {
    unsigned u = __builtin_bit_cast(unsigned, f);
    unsigned r = u + 0x7FFFu + ((u >> 16) & 1u);
    return (short)(r >> 16);
}

__device__ __forceinline__ void gld_lds16(const void* g, void* l) {
    __builtin_amdgcn_global_load_lds((const __attribute__((address_space(1))) unsigned int*)g,
                                     (__attribute__((address_space(3))) unsigned int*)l, 16, 0, 0);
}

template<int CTRL>
__device__ __forceinline__ unsigned dppmax(unsigned x) {
    unsigned y = (unsigned)__builtin_amdgcn_update_dpp(0, (int)x, CTRL, 0xF, 0xF, true);
    return x > y ? x : y;
}

// ---------------------------------------------------------------- prep ------
__global__ __launch_bounds__(256) void k_prep(const float* __restrict__ bank,
        const float* __restrict__ W1, const float* __restrict__ W2,
        short* __restrict__ bnbf, double* __restrict__ binv,
        short* __restrict__ w1bf, short* __restrict__ w2bf)
{
    __shared__ double part[4];
    __shared__ double s_inv;
    const int bid = blockIdx.x, t = threadIdx.x;
    if (bid < 1024) {
        const int row = bid;
        if (row < 1000) {
            float v = bank[(size_t)row * DIM + t];
            double ssq = (double)v * (double)v;
            for (int o = 32; o > 0; o >>= 1) ssq += __shfl_down(ssq, o);
            if ((t & 63) == 0) part[t >> 6] = ssq;
            __syncthreads();
            if (t == 0) {
                double s = part[0] + part[1] + part[2] + part[3];
                double n = sqrt(s); if (n < 1e-12) n = 1e-12;
                double inv = 1.0 / n;
                binv[row] = inv; s_inv = inv;
            }
            __syncthreads();
            const int pcol = (((t >> 3) ^ (row & 7)) << 3) | (t & 7);
            bnbf[(size_t)row * DIM + pcol] = f32bf((float)((double)v * s_inv));
        } else {
            bnbf[(size_t)row * DIM + t] = 0;
            if (t == 0) binv[row] = 0.0;
        }
    } else if (bid < 1536) {
        const int i = (bid - 1024) * 256 + t;
        w1bf[i] = f32bf(W1[i]);
    } else {
        const int i = (bid - 1536) * 256 + t;
        w2bf[i] = f32bf(W2[i]);
    }
}

// ---------------------------------------------------------------- sims ------
__global__ __launch_bounds__(256) void k_sims(const float* __restrict__ feat,
        const short* __restrict__ bnbf, short* __restrict__ sims, int qoff)
{
    __shared__ alignas(16) short Qs[64 * 264];
    __shared__ alignas(16) short Ab[64 * 256];
    const int t = threadIdx.x, lane = t & 63, w = t >> 6;
    const int n16 = lane & 15, q4 = lane >> 4;

    {
        const int r = t >> 2, p = t & 3;
        const float4* src = (const float4*)(feat + (size_t)(qoff + blockIdx.x * 64 + r) * DIM + p * 64);
        short* dst = Qs + r * 264 + p * 64;
        #pragma unroll
        for (int i = 0; i < 16; ++i) {
            float4 v = src[i];
            dst[i*4+0] = f32bf(v.x); dst[i*4+1] = f32bf(v.y);
            dst[i*4+2] = f32bf(v.z); dst[i*4+3] = f32bf(v.w);
        }
    }
    const char* gA = (const char*)bnbf;
    char* lA = (char*)Ab;
    #pragma unroll
    for (int i = 0; i < 8; ++i)
        gld_lds16(gA + i * 4096 + t * 16, lA + i * 4096 + (t >> 6) * 1024);
    __syncthreads();

    short8 bq[8][4];
    #pragma unroll
    for (int kc = 0; kc < 8; ++kc)
        #pragma unroll
        for (int nt = 0; nt < 4; ++nt)
            bq[kc][nt] = *(const short8*)(Qs + (nt * 16 + n16) * 264 + kc * 32 + q4 * 8);

    const int ml = w * 16 + n16;
    int aoff[8];
    #pragma unroll
    for (int kc = 0; kc < 8; ++kc)
        aoff[kc] = (ml * 256 + (((kc * 4 + q4) ^ (ml & 7)) << 3)) * 2;

    const f32x4 vzero = {0.f, 0.f, 0.f, 0.f};
    for (int chunk = 0; chunk < 16; ++chunk) {
        f32x4 acc[4];
        acc[0] = vzero; acc[1] = vzero; acc[2] = vzero; acc[3] = vzero;
        #pragma unroll
        for (int kc = 0; kc < 8; ++kc) {
            short8 af = *(const short8*)(lA + aoff[kc]);
            #pragma unroll
            for (int nt = 0; nt < 4; ++nt)
                acc[nt] = __builtin_amdgcn_mfma_f32_16x16x32_bf16(af, bq[kc][nt], acc[nt], 0, 0, 0);
        }
        const int bankb = chunk * 64 + w * 16 + q4 * 4;
        #pragma unroll
        for (int nt = 0; nt < 4; ++nt) {
            const int qc = blockIdx.x * 64 + nt * 16 + n16;
            uint2 u;
            u.x = ((unsigned)(unsigned short)f32bf(acc[nt][0])) |
                  (((unsigned)(unsigned short)f32bf(acc[nt][1])) << 16);
            u.y = ((unsigned)(unsigned short)f32bf(acc[nt][2])) |
                  (((unsigned)(unsigned short)f32bf(acc[nt][3])) << 16);
            *(uint2*)(sims + (size_t)qc * 1024 + bankb) = u;
        }
        __syncthreads();
        if (chunk < 15) {
            #pragma unroll
            for (int i = 0; i < 8; ++i)
                gld_lds16(gA + (size_t)(chunk + 1) * 32768 + i * 4096 + t * 16,
                          lA + i * 4096 + (t >> 6) * 1024);
            __syncthreads();
        }
    }
}

// -------------------------------------------------------------- select ------
__global__ __launch_bounds__(256) void k_select(const short* __restrict__ sims,
        int* __restrict__ top, int qoff)
{
    const int t = threadIdx.x, lane = t & 63, w = t >> 6;
    const int q = blockIdx.x * 4 + w;
    const uint4* p = (const uint4*)(sims + (size_t)q * 1024 + lane * 16);
    uint4 a = p[0], b = p[1];

    unsigned k[16];
    {
        unsigned words[8] = {a.x, a.y, a.z, a.w, b.x, b.y, b.z, b.w};
        #pragma unroll
        for (int j = 0; j < 16; ++j) {
            unsigned h = (j & 1) ? (words[j >> 1] >> 16) : (words[j >> 1] & 0xFFFFu);
            unsigned m = (h ^ 0x8000u) ^ ((0u - (h >> 15)) & 0x7FFFu);
            int idx = lane * 16 + j;
            k[j] = (idx < 1000) ? ((m << 16) | (unsigned)idx) : 0u;
        }
    }
    #pragma unroll
    for (int sz = 2; sz <= 16; sz <<= 1)
        #pragma unroll
        for (int st = sz >> 1; st >= 1; st >>= 1)
            #pragma unroll
            for (int i = 0; i < 16; ++i) {
                int j = i ^ st;
                if (j > i) {
                    bool desc = ((i & sz) == 0);
                    unsigned lo = k[i], hi = k[j];
                    unsigned mx = lo > hi ? lo : hi;
                    unsigned mn = lo > hi ? hi : lo;
                    k[i] = desc ? mx : mn;
                    k[j] = desc ? mn : mx;
                }
            }
    unsigned mine = 0;
    #pragma unroll
    for (int r = 0; r < 12; ++r) {
        unsigned m = k[0];
        m = dppmax<0xB1>(m);
        m = dppmax<0x4E>(m);
        m = dppmax<0x141>(m);
        m = dppmax<0x140>(m);
        m = dppmax<0x142>(m);
        m = dppmax<0x143>(m);
        unsigned wm = (unsigned)__builtin_amdgcn_readlane((int)m, 63);
        if (lane == r) mine = wm;
        if (k[0] == wm) {
            #pragma unroll
            for (int s = 0; s < 12; ++s) k[s] = k[s + 1];
        }
    }
    if (lane < 12) top[(size_t)(qoff + q) * NC + lane] = (int)(mine & 0xFFFFu);
}

// -------------------------------------------------------------- refine ------
// 16 queries per block (q = blockIdx.x*16 + w*4 + (lane>>4) -- the thread map
// spans exactly 0..15; round-6's 64-q/block launch left 75% of nf unwritten).
// Phases: (1) fp32 dots 16-lanes/query -> LDS; (2) t<16 scalar keys/ranks/
// gap/softmax/compact; (3) masked fp64 re-dot for flagged (gap < 2e-6);
// (4) flagged re-rank; (5) 5-row weighted gather -> nf bf16.
__global__ __launch_bounds__(256) void k_refine(const float* __restrict__ feat,
        const float* __restrict__ bank, const int* __restrict__ top,
        const double* __restrict__ binv, short* __restrict__ nf)
{
    __shared__ int    cidxL[16 * NC];
    __shared__ float  bdF[16 * NC];
    __shared__ double bdD[16 * NC];
    __shared__ float  simsF[16 * NC];
    __shared__ double simsD[16 * NC];
    __shared__ float  qiL[16];
    __shared__ int    flagL[16];
    __shared__ int    selidx[16][5];
    __shared__ float  selw[16][5];

    const int t = threadIdx.x, lane = t & 63, w = t >> 6;
    const int g = lane >> 4, u = lane & 15;
    const int ql = w * 4 + g;                 // 0..15
    const int qbase = blockIdx.x * 16;
    const int q = qbase + ql;

    // cooperative load of candidate indices + norms (192 entries)
    if (t < 16 * NC) {
        const int c = top[(size_t)qbase * NC + t];
        cidxL[t] = c;
        const double b = binv[c];
        bdD[t] = b; bdF[t] = (float)b;
    }
    __syncthreads();

    int ci[NC];
    #pragma unroll
    for (int c = 0; c < NC; ++c) ci[c] = cidxL[ql * NC + c];

    // ---- phase 1: fp32 dots ----
    float qf[16];
    float ssf = 0.f;
    #pragma unroll
    for (int j = 0; j < 4; ++j) {
        float4 v = *(const float4*)(feat + (size_t)q * DIM + j * 64 + u * 4);
        qf[j*4+0] = v.x; qf[j*4+1] = v.y; qf[j*4+2] = v.z; qf[j*4+3] = v.w;
        ssf += v.x*v.x + v.y*v.y + v.z*v.z + v.w*v.w;
    }
    #pragma unroll
    for (int o = 1; o < 16; o <<= 1) ssf += __shfl_xor(ssf, o, 16);
    float nq = sqrtf(ssf); if (nq < 1e-12f) nq = 1e-12f;
    if (u == 0) qiL[ql] = 1.f / nq;

    float s[NC];
    #pragma unroll
    for (int c = 0; c < NC; ++c) {
        const float* brow = bank + (size_t)ci[c] * DIM + u * 4;
        float a0 = 0.f, a1 = 0.f, a2 = 0.f, a3 = 0.f;
        #pragma unroll
        for (int j = 0; j < 4; ++j) {
            float4 b = *(const float4*)(brow + j * 64);
            a0 += qf[j*4+0] * b.x; a1 += qf[j*4+1] * b.y;
            a2 += qf[j*4+2] * b.z; a3 += qf[j*4+3] * b.w;
        }
        s[c] = (a0 + a1) + (a2 + a3);
    }
    #pragma unroll
    for (int o = 1; o < 16; o <<= 1)
        #pragma unroll
        for (int c = 0; c < NC; ++c) s[c] += __shfl_xor(s[c], o, 16);
    #pragma unroll
    for (int c = 0; c < NC; ++c) if (u == c) simsF[ql * NC + c] = s[c];
    __syncthreads();

    // ---- phase 2: per-query scalar (1 thread/query) ----
    if (t < 16) {
        const float qi2 = qiL[t];
        float vf[NC];
        unsigned long long key[NC];
        int cid[NC];
        #pragma unroll
        for (int c = 0; c < NC; ++c) {
            cid[c] = cidxL[t * NC + c];
            float v = simsF[t * NC + c] * qi2 * bdF[t * NC + c];
            vf[c] = v;
            unsigned ub = __builtin_bit_cast(unsigned, v);
            unsigned m = (ub >> 31) ? ~ub : (ub | 0x80000000u);
            key[c] = ((unsigned long long)m << 10) | (unsigned long long)(1023 - cid[c]);
        }
        int rank[NC];
        #pragma unroll
        for (int c = 0; c < NC; ++c) rank[c] = 0;
        #pragma unroll
        for (int c1 = 0; c1 < NC; ++c1)
            #pragma unroll
            for (int c2 = c1 + 1; c2 < NC; ++c2) {
                const bool gt = key[c1] > key[c2];
                rank[c2] += gt ? 1 : 0;
                rank[c1] += gt ? 0 : 1;
            }
        float v5 = 0.f, v6 = 0.f;
        #pragma unroll
        for (int c = 0; c < NC; ++c) {
            v5 += (rank[c] == 4) ? vf[c] : 0.f;
            v6 += (rank[c] == 5) ? vf[c] : 0.f;
        }
        flagL[t] = (v5 - v6) < 2e-6f;

        float vm = vf[0];
        #pragma unroll
        for (int c = 1; c < NC; ++c) vm = fmaxf(vm, vf[c]);
        float e[NC]; float wsum = 0.f;
        #pragma unroll
        for (int c = 0; c < NC; ++c) {
            float ex = __expf(vf[c] - vm);
            ex = (rank[c] < 5) ? ex : 0.f;
            e[c] = ex; wsum += ex;
        }
        const float inv = 1.f / wsum;
        #pragma unroll
        for (int k = 0; k < 5; ++k) {
            int idx = 0; float wv = 0.f;
            #pragma unroll
            for (int c = 0; c < NC; ++c) {
                const bool is = (rank[c] == k);
                idx += is ? cid[c] : 0;
                wv  += is ? e[c]  : 0.f;
            }
            selidx[t][k] = idx; selw[t][k] = wv * inv;
        }
    }
    __syncthreads();

    // ---- phase 3: rare fp64 re-dot (exec-masked per 16-lane group) ----
    if (flagL[ql]) {
        double ssd = 0.0;
        #pragma unroll
        for (int j = 0; j < 16; ++j) ssd += (double)qf[j] * (double)qf[j];
        #pragma unroll
        for (int o = 1; o < 16; o <<= 1) ssd += __shfl_xor(ssd, o, 16);
        double nd = sqrt(ssd); if (nd < 1e-12) nd = 1e-12;
        const double qid = 1.0 / nd;
        double sd[NC];
        #pragma unroll
        for (int c = 0; c < NC; ++c) {
            const float* brow = bank + (size_t)ci[c] * DIM + u * 4;
            double a0 = 0, a1 = 0, a2 = 0, a3 = 0;
            #pragma unroll
            for (int j = 0; j < 4; ++j) {
                float4 b = *(const float4*)(brow + j * 64);
                a0 += (double)qf[j*4+0] * b.x; a1 += (double)qf[j*4+1] * b.y;
                a2 += (double)qf[j*4+2] * b.z; a3 += (double)qf[j*4+3] * b.w;
            }
            sd[c] = (a0 + a1) + (a2 + a3);
        }
        #pragma unroll
        for (int o = 1; o < 16; o <<= 1)
            #pragma unroll
            for (int c = 0; c < NC; ++c) sd[c] += __shfl_xor(sd[c], o, 16);
        #pragma unroll
        for (int c = 0; c < NC; ++c)
            if (u == c) simsD[ql * NC + c] = sd[c] * qid * bdD[ql * NC + c];
    }
    __syncthreads();

    // ---- phase 4: flagged re-rank (1 thread/query) ----
    if (t < 16 && flagL[t]) {
        double vd[NC];
        unsigned long long key[NC];
        int cid[NC];
        #pragma unroll
        for (int c = 0; c < NC; ++c) {
            cid[c] = cidxL[t * NC + c];
            double v = simsD[t * NC + c];
            vd[c] = v;
            unsigned long long ub = __builtin_bit_cast(unsigned long long, v);
            unsigned long long m = (ub >> 63) ? ~ub : (ub | 0x8000000000000000ULL);
            key[c] = (m & ~0x3FFULL) | (unsigned long long)(1023 - cid[c]);
        }
        int rank[NC];
        #pragma unroll
        for (int c = 0; c < NC; ++c) rank[c] = 0;
        #pragma unroll
        for (int c1 = 0; c1 < NC; ++c1)
            #pragma unroll
            for (int c2 = c1 + 1; c2 < NC; ++c2) {
                const bool gt = key[c1] > key[c2];
                rank[c2] += gt ? 1 : 0;
                rank[c1] += gt ? 0 : 1;
            }
        float vf[NC];
        #pragma unroll
        for (int c = 0; c < NC; ++c) vf[c] = (float)vd[c];
        float vm = vf[0];
        #pragma unroll
        for (int c = 1; c < NC; ++c) vm = fmaxf(vm, vf[c]);
        float e[NC]; float wsum = 0.f;
        #pragma unroll
        for (int c = 0; c < NC; ++c) {
            float ex = __expf(vf[c] - vm);
            ex = (rank[c] < 5) ? ex : 0.f;
            e[c] = ex; wsum += ex;
        }
        const float inv = 1.f / wsum;
        #pragma unroll
        for (int k = 0; k < 5; ++k) {
            int idx = 0; float wv = 0.f;
            #pragma unroll
            for (int c = 0; c < NC; ++c) {
                const bool is = (rank[c] == k);
                idx += is ? cid[c] : 0;
                wv  += is ? e[c]  : 0.f;
            }
            selidx[t][k] = idx; selw[t][k] = wv * inv;
        }
    }
    __syncthreads();

    // ---- phase 5: 5-row weighted gather ----
    float wk[5]; int ik[5];
    #pragma unroll
    for (int k = 0; k < 5; ++k) { wk[k] = selw[ql][k]; ik[k] = selidx[ql][k]; }
    float4 oa[4];
    #pragma unroll
    for (int j = 0; j < 4; ++j) { oa[j].x = 0.f; oa[j].y = 0.f; oa[j].z = 0.f; oa[j].w = 0.f; }
    #pragma unroll
    for (int k = 0; k < 5; ++k) {
        const float wc = wk[k];
        const float* brow = bank + (size_t)ik[k] * DIM + u * 4;
        #pragma unroll
        for (int j = 0; j < 4; ++j) {
            float4 b = *(const float4*)(brow + j * 64);
            oa[j].x += wc * b.x; oa[j].y += wc * b.y;
            oa[j].z += wc * b.z; oa[j].w += wc * b.w;
        }
    }
    short* od = nf + (size_t)q * DIM + u * 4;
    #pragma unroll
    for (int j = 0; j < 4; ++j) {
        uint2 pk;
        pk.x = ((unsigned)(unsigned short)f32bf(oa[j].x)) |
               (((unsigned)(unsigned short)f32bf(oa[j].y)) << 16);
        pk.y = ((unsigned)(unsigned short)f32bf(oa[j].z)) |
               (((unsigned)(unsigned short)f32bf(oa[j].w)) << 16);
        *(uint2*)(od + j * 64) = pk;
    }
}

// ---------------------------------------------------------- fused MLP -------
// Block = 64 rows. Phase 1: h = relu([feat|nf]@W1^T + b1) -> LDS (never HBM).
// Phase 2: out = h@W2^T + b2 -> global fp32. Saves the 67 MB h round-trip.
__global__ __launch_bounds__(256) void k_mlp(const float* __restrict__ feat,
        const short* __restrict__ nf, const short* __restrict__ w1bf,
        const short* __restrict__ w2bf, const float* __restrict__ b1,
        const float* __restrict__ b2, float* __restrict__ out)
{
    __shared__ alignas(16) short As[64 * 40];
    __shared__ alignas(16) short Bs[256 * 40];
    __shared__ alignas(16) short Hs[64 * 264];
    const int t = threadIdx.x, lane = t & 63, w = t >> 6;
    const int mb = blockIdx.x * 64;
    const int r = t >> 2, p = t & 3;
    const int n16 = lane & 15, ko = (lane >> 4) << 3;
    const int rq = (lane >> 4) << 2, cc = lane & 15;
    const f32x4 vzero = {0.f, 0.f, 0.f, 0.f};

    f32x4 acc[4][4];
    #pragma unroll
    for (int a = 0; a < 4; ++a)
        #pragma unroll
        for (int b = 0; b < 4; ++b) acc[a][b] = vzero;

    // ---- layer 1 ----
    for (int kc = 0; kc < 16; ++kc) {
        short* ad = As + r * 40 + p * 8;
        if (kc < 8) {
            const float4* s = (const float4*)(feat + (size_t)(mb + r) * 256 + kc * 32 + p * 8);
            float4 v0 = s[0], v1 = s[1];
            ad[0] = f32bf(v0.x); ad[1] = f32bf(v0.y); ad[2] = f32bf(v0.z); ad[3] = f32bf(v0.w);
            ad[4] = f32bf(v1.x); ad[5] = f32bf(v1.y); ad[6] = f32bf(v1.z); ad[7] = f32bf(v1.w);
        } else {
            *(uint4*)ad = *(const uint4*)(nf + (size_t)(mb + r) * 256 + (kc - 8) * 32 + p * 8);
        }
        {
            const uint4* bsrc = (const uint4*)(w1bf + (size_t)t * 512 + kc * 32);
            short* bdst = Bs + t * 40;
            *(uint4*)(bdst +  0) = bsrc[0];
            *(uint4*)(bdst +  8) = bsrc[1];
            *(uint4*)(bdst + 16) = bsrc[2];
            *(uint4*)(bdst + 24) = bsrc[3];
        }
        __syncthreads();
        short8 af[4], bf[4];
        #pragma unroll
        for (int mt = 0; mt < 4; ++mt)
            af[mt] = *(const short8*)(As + (mt * 16 + n16) * 40 + ko);
        #pragma unroll
        for (int nt = 0; nt < 4; ++nt)
            bf[nt] = *(const short8*)(Bs + (w * 64 + nt * 16 + n16) * 40 + ko);
        #pragma unroll
        for (int mt = 0; mt < 4; ++mt)
            #pragma unroll
            for (int nt = 0; nt < 4; ++nt)
                acc[mt][nt] = __builtin_amdgcn_mfma_f32_16x16x32_bf16(af[mt], bf[nt], acc[mt][nt], 0, 0, 0);
        __syncthreads();
    }
    // epilogue 1: bias + relu -> Hs (LDS)
    #pragma unroll
    for (int mt = 0; mt < 4; ++mt)
        #pragma unroll
        for (int nt = 0; nt < 4; ++nt) {
            const int row = mt * 16 + rq;
            const int col = w * 64 + nt * 16 + cc;
            const float bias = b1[col];
            #pragma unroll
            for (int rr = 0; rr < 4; ++rr) {
                float v = acc[mt][nt][rr] + bias;
                Hs[(row + rr) * 264 + col] = f32bf(fmaxf(v, 0.f));
            }
        }
    #pragma unroll
    for (int a = 0; a < 4; ++a)
        #pragma unroll
        for (int b = 0; b < 4; ++b) acc[a][b] = vzero;
    __syncthreads();

    // ---- layer 2 ----
    for (int kc = 0; kc < 8; ++kc) {
        {
            const uint4* bsrc = (const uint4*)(w2bf + (size_t)t * 256 + kc * 32);
            short* bdst = Bs + t * 40;
            *(uint4*)(bdst +  0) = bsrc[0];
            *(uint4*)(bdst +  8) = bsrc[1];
            *(uint4*)(bdst + 16) = bsrc[2];
            *(uint4*)(bdst + 24) = bsrc[3];
        }
        __syncthreads();
        short8 af[4], bf[4];
        #pragma unroll
        for (int mt = 0; mt < 4; ++mt)
            af[mt] = *(const short8*)(Hs + (mt * 16 + n16) * 264 + kc * 32 + ko);
        #pragma unroll
        for (int nt = 0; nt < 4; ++nt)
            bf[nt] = *(const short8*)(Bs + (w * 64 + nt * 16 + n16) * 40 + ko);
        #pragma unroll
        for (int mt = 0; mt < 4; ++mt)
            #pragma unroll
            for (int nt = 0; nt < 4; ++nt)
                acc[mt][nt] = __builtin_amdgcn_mfma_f32_16x16x32_bf16(af[mt], bf[nt], acc[mt][nt], 0, 0, 0);
        __syncthreads();
    }
    #pragma unroll
    for (int mt = 0; mt < 4; ++mt)
        #pragma unroll
        for (int nt = 0; nt < 4; ++nt) {
            const int row = mb + mt * 16 + rq;
            const int col = w * 64 + nt * 16 + cc;
            const float bias = b2[col];
            #pragma unroll
            for (int rr = 0; rr < 4; ++rr)
                out[(size_t)(row + rr) * 256 + col] = acc[mt][nt][rr] + bias;
        }
}

// ------------------------------------------------------------- launcher -----
extern "C" void kernel_launch(void* const* d_in, const int* in_sizes, int n_in,
                              void* d_out, int out_size, void* d_ws, size_t ws_size,
                              hipStream_t stream) {
    const float* feat = (const float*)d_in[0];
    const float* bank = (const float*)d_in[1];
    const float* W1   = (const float*)d_in[2];
    const float* b1   = (const float*)d_in[3];
    const float* W2   = (const float*)d_in[4];
    const float* b2   = (const float*)d_in[5];
    float* out = (float*)d_out;

    char* ws = (char*)d_ws;
    short*  bnbf = (short*)(ws + 0);              // 1024*256*2   = 524288
    double* binv = (double*)(ws + 524288);        // 1024*8       = 8192
    short*  w1bf = (short*)(ws + 532480);         // 131072*2     = 262144
    short*  w2bf = (short*)(ws + 794624);         // 65536*2      = 131072
    int*    top  = (int*)(ws + 925696);           // 65536*12*4   = 3145728
    short*  nf   = (short*)(ws + 4071424);        // 65536*256*2  = 33554432
    short*  X    = (short*)(ws + 37625856);       // 33554432: sims slices
    // total 71180288 bytes

    k_prep<<<1792, 256, 0, stream>>>(bank, W1, W2, bnbf, binv, w1bf, w2bf);
    for (int s = 0; s < 4; ++s) {
        const int qoff = s * 16384;
        k_sims  <<<256,  256, 0, stream>>>(feat, bnbf, X, qoff);
        k_select<<<4096, 256, 0, stream>>>(X, top, qoff);
    }
    k_refine<<<4096, 256, 0, stream>>>(feat, bank, top, binv, nf);
    k_mlp   <<<1024, 256, 0, stream>>>(feat, nf, w1bf, w2bf, b1, b2, out);
}

// Round 8
// 384.994 us; speedup vs baseline: 1.1271x; 1.0586x over previous
//
#include <hip/hip_runtime.h>

#define DIM 256
#define NC 12

typedef __attribute__((ext_vector_type(8))) short short8;
typedef __attribute__((ext_vector_type(4))) float f32x4;

__device__ __forceinline__ short f32bf(float f) {
    unsigned u = __builtin_bit_cast(unsigned, f);
    unsigned r = u + 0x7FFFu + ((u >> 16) & 1u);
    return (short)(r >> 16);
}

__device__ __forceinline__ void gld_lds16(const void* g, void* l) {
    __builtin_amdgcn_global_load_lds((const __attribute__((address_space(1))) unsigned int*)g,
                                     (__attribute__((address_space(3))) unsigned int*)l, 16, 0, 0);
}

template<int CTRL>
__device__ __forceinline__ unsigned dppmax(unsigned x) {
    unsigned y = (unsigned)__builtin_amdgcn_update_dpp(0, (int)x, CTRL, 0xF, 0xF, true);
    return x > y ? x : y;
}

// ---------------------------------------------------------------- prep ------
__global__ __launch_bounds__(256) void k_prep(const float* __restrict__ bank,
        const float* __restrict__ W1, const float* __restrict__ W2,
        short* __restrict__ bnbf, double* __restrict__ binv,
        short* __restrict__ w1bf, short* __restrict__ w2bf)
{
    __shared__ double part[4];
    __shared__ double s_inv;
    const int bid = blockIdx.x, t = threadIdx.x;
    if (bid < 1024) {
        const int row = bid;
        if (row < 1000) {
            float v = bank[(size_t)row * DIM + t];
            double ssq = (double)v * (double)v;
            for (int o = 32; o > 0; o >>= 1) ssq += __shfl_down(ssq, o);
            if ((t & 63) == 0) part[t >> 6] = ssq;
            __syncthreads();
            if (t == 0) {
                double s = part[0] + part[1] + part[2] + part[3];
                double n = sqrt(s); if (n < 1e-12) n = 1e-12;
                double inv = 1.0 / n;
                binv[row] = inv; s_inv = inv;
            }
            __syncthreads();
            const int pcol = (((t >> 3) ^ (row & 7)) << 3) | (t & 7);
            bnbf[(size_t)row * DIM + pcol] = f32bf((float)((double)v * s_inv));
        } else {
            bnbf[(size_t)row * DIM + t] = 0;
            if (t == 0) binv[row] = 0.0;
        }
    } else if (bid < 1536) {
        const int i = (bid - 1024) * 256 + t;
        w1bf[i] = f32bf(W1[i]);
    } else {
        const int i = (bid - 1536) * 256 + t;
        w2bf[i] = f32bf(W2[i]);
    }
}

// ---------------------------------------------------------------- sims ------
// 32 queries/block, 512 blocks/slice -> 2 blocks/CU so the per-chunk
// vmcnt(0)+barrier drains overlap across blocks (was 1 block/CU).
__global__ __launch_bounds__(256) void k_sims(const float* __restrict__ feat,
        const short* __restrict__ bnbf, short* __restrict__ sims, int qoff)
{
    __shared__ alignas(16) short Qs[32 * 264];
    __shared__ alignas(16) short Ab[64 * 256];
    const int t = threadIdx.x, lane = t & 63, w = t >> 6;
    const int n16 = lane & 15, q4 = lane >> 4;

    {
        const int r = t >> 3, p = t & 7;
        const float4* src = (const float4*)(feat + (size_t)(qoff + blockIdx.x * 32 + r) * DIM + p * 32);
        short* dst = Qs + r * 264 + p * 32;
        #pragma unroll
        for (int i = 0; i < 8; ++i) {
            float4 v = src[i];
            dst[i*4+0] = f32bf(v.x); dst[i*4+1] = f32bf(v.y);
            dst[i*4+2] = f32bf(v.z); dst[i*4+3] = f32bf(v.w);
        }
    }
    const char* gA = (const char*)bnbf;
    char* lA = (char*)Ab;
    #pragma unroll
    for (int i = 0; i < 8; ++i)
        gld_lds16(gA + i * 4096 + t * 16, lA + i * 4096 + (t >> 6) * 1024);
    __syncthreads();

    short8 bq[8][2];
    #pragma unroll
    for (int kc = 0; kc < 8; ++kc)
        #pragma unroll
        for (int nt = 0; nt < 2; ++nt)
            bq[kc][nt] = *(const short8*)(Qs + (nt * 16 + n16) * 264 + kc * 32 + q4 * 8);

    const int ml = w * 16 + n16;
    int aoff[8];
    #pragma unroll
    for (int kc = 0; kc < 8; ++kc)
        aoff[kc] = (ml * 256 + (((kc * 4 + q4) ^ (ml & 7)) << 3)) * 2;

    const f32x4 vzero = {0.f, 0.f, 0.f, 0.f};
    for (int chunk = 0; chunk < 16; ++chunk) {
        f32x4 acc[2];
        acc[0] = vzero; acc[1] = vzero;
        #pragma unroll
        for (int kc = 0; kc < 8; ++kc) {
            short8 af = *(const short8*)(lA + aoff[kc]);
            #pragma unroll
            for (int nt = 0; nt < 2; ++nt)
                acc[nt] = __builtin_amdgcn_mfma_f32_16x16x32_bf16(af, bq[kc][nt], acc[nt], 0, 0, 0);
        }
        const int bankb = chunk * 64 + w * 16 + q4 * 4;
        #pragma unroll
        for (int nt = 0; nt < 2; ++nt) {
            const int qc = blockIdx.x * 32 + nt * 16 + n16;
            uint2 u;
            u.x = ((unsigned)(unsigned short)f32bf(acc[nt][0])) |
                  (((unsigned)(unsigned short)f32bf(acc[nt][1])) << 16);
            u.y = ((unsigned)(unsigned short)f32bf(acc[nt][2])) |
                  (((unsigned)(unsigned short)f32bf(acc[nt][3])) << 16);
            *(uint2*)(sims + (size_t)qc * 1024 + bankb) = u;
        }
        __syncthreads();
        if (chunk < 15) {
            #pragma unroll
            for (int i = 0; i < 8; ++i)
                gld_lds16(gA + (size_t)(chunk + 1) * 32768 + i * 4096 + t * 16,
                          lA + i * 4096 + (t >> 6) * 1024);
            __syncthreads();
        }
    }
}

// -------------------------------------------------------------- select ------
__global__ __launch_bounds__(256) void k_select(const short* __restrict__ sims,
        int* __restrict__ top, int qoff)
{
    const int t = threadIdx.x, lane = t & 63, w = t >> 6;
    const int q = blockIdx.x * 4 + w;
    const uint4* p = (const uint4*)(sims + (size_t)q * 1024 + lane * 16);
    uint4 a = p[0], b = p[1];

    unsigned k[16];
    {
        unsigned words[8] = {a.x, a.y, a.z, a.w, b.x, b.y, b.z, b.w};
        #pragma unroll
        for (int j = 0; j < 16; ++j) {
            unsigned h = (j & 1) ? (words[j >> 1] >> 16) : (words[j >> 1] & 0xFFFFu);
            unsigned m = (h ^ 0x8000u) ^ ((0u - (h >> 15)) & 0x7FFFu);
            int idx = lane * 16 + j;
            k[j] = (idx < 1000) ? ((m << 16) | (unsigned)idx) : 0u;
        }
    }
    #pragma unroll
    for (int sz = 2; sz <= 16; sz <<= 1)
        #pragma unroll
        for (int st = sz >> 1; st >= 1; st >>= 1)
            #pragma unroll
            for (int i = 0; i < 16; ++i) {
                int j = i ^ st;
                if (j > i) {
                    bool desc = ((i & sz) == 0);
                    unsigned lo = k[i], hi = k[j];
                    unsigned mx = lo > hi ? lo : hi;
                    unsigned mn = lo > hi ? hi : lo;
                    k[i] = desc ? mx : mn;
                    k[j] = desc ? mn : mx;
                }
            }
    unsigned mine = 0;
    #pragma unroll
    for (int r = 0; r < 12; ++r) {
        unsigned m = k[0];
        m = dppmax<0xB1>(m);
        m = dppmax<0x4E>(m);
        m = dppmax<0x141>(m);
        m = dppmax<0x140>(m);
        m = dppmax<0x142>(m);
        m = dppmax<0x143>(m);
        unsigned wm = (unsigned)__builtin_amdgcn_readlane((int)m, 63);
        if (lane == r) mine = wm;
        if (k[0] == wm) {
            #pragma unroll
            for (int s = 0; s < 12; ++s) k[s] = k[s + 1];
        }
    }
    if (lane < 12) top[(size_t)(qoff + q) * NC + lane] = (int)(mine & 0xFFFFu);
}

// -------------------------------------------------------------- refine ------
__global__ __launch_bounds__(256) void k_refine(const float* __restrict__ feat,
        const float* __restrict__ bank, const int* __restrict__ top,
        const double* __restrict__ binv, short* __restrict__ nf)
{
    __shared__ int    cidxL[16 * NC];
    __shared__ float  bdF[16 * NC];
    __shared__ double bdD[16 * NC];
    __shared__ float  simsF[16 * NC];
    __shared__ double simsD[16 * NC];
    __shared__ float  qiL[16];
    __shared__ int    flagL[16];
    __shared__ int    selidx[16][5];
    __shared__ float  selw[16][5];

    const int t = threadIdx.x, lane = t & 63, w = t >> 6;
    const int g = lane >> 4, u = lane & 15;
    const int ql = w * 4 + g;
    const int qbase = blockIdx.x * 16;
    const int q = qbase + ql;

    if (t < 16 * NC) {
        const int c = top[(size_t)qbase * NC + t];
        cidxL[t] = c;
        const double b = binv[c];
        bdD[t] = b; bdF[t] = (float)b;
    }
    __syncthreads();

    int ci[NC];
    #pragma unroll
    for (int c = 0; c < NC; ++c) ci[c] = cidxL[ql * NC + c];

    float qf[16];
    float ssf = 0.f;
    #pragma unroll
    for (int j = 0; j < 4; ++j) {
        float4 v = *(const float4*)(feat + (size_t)q * DIM + j * 64 + u * 4);
        qf[j*4+0] = v.x; qf[j*4+1] = v.y; qf[j*4+2] = v.z; qf[j*4+3] = v.w;
        ssf += v.x*v.x + v.y*v.y + v.z*v.z + v.w*v.w;
    }
    #pragma unroll
    for (int o = 1; o < 16; o <<= 1) ssf += __shfl_xor(ssf, o, 16);
    float nq = sqrtf(ssf); if (nq < 1e-12f) nq = 1e-12f;
    if (u == 0) qiL[ql] = 1.f / nq;

    float s[NC];
    #pragma unroll
    for (int c = 0; c < NC; ++c) {
        const float* brow = bank + (size_t)ci[c] * DIM + u * 4;
        float a0 = 0.f, a1 = 0.f, a2 = 0.f, a3 = 0.f;
        #pragma unroll
        for (int j = 0; j < 4; ++j) {
            float4 b = *(const float4*)(brow + j * 64);
            a0 += qf[j*4+0] * b.x; a1 += qf[j*4+1] * b.y;
            a2 += qf[j*4+2] * b.z; a3 += qf[j*4+3] * b.w;
        }
        s[c] = (a0 + a1) + (a2 + a3);
    }
    #pragma unroll
    for (int o = 1; o < 16; o <<= 1)
        #pragma unroll
        for (int c = 0; c < NC; ++c) s[c] += __shfl_xor(s[c], o, 16);
    #pragma unroll
    for (int c = 0; c < NC; ++c) if (u == c) simsF[ql * NC + c] = s[c];
    __syncthreads();

    if (t < 16) {
        const float qi2 = qiL[t];
        float vf[NC];
        unsigned long long key[NC];
        int cid[NC];
        #pragma unroll
        for (int c = 0; c < NC; ++c) {
            cid[c] = cidxL[t * NC + c];
            float v = simsF[t * NC + c] * qi2 * bdF[t * NC + c];
            vf[c] = v;
            unsigned ub = __builtin_bit_cast(unsigned, v);
            unsigned m = (ub >> 31) ? ~ub : (ub | 0x80000000u);
            key[c] = ((unsigned long long)m << 10) | (unsigned long long)(1023 - cid[c]);
        }
        int rank[NC];
        #pragma unroll
        for (int c = 0; c < NC; ++c) rank[c] = 0;
        #pragma unroll
        for (int c1 = 0; c1 < NC; ++c1)
            #pragma unroll
            for (int c2 = c1 + 1; c2 < NC; ++c2) {
                const bool gt = key[c1] > key[c2];
                rank[c2] += gt ? 1 : 0;
                rank[c1] += gt ? 0 : 1;
            }
        float v5 = 0.f, v6 = 0.f;
        #pragma unroll
        for (int c = 0; c < NC; ++c) {
            v5 += (rank[c] == 4) ? vf[c] : 0.f;
            v6 += (rank[c] == 5) ? vf[c] : 0.f;
        }
        flagL[t] = (v5 - v6) < 2e-6f;

        float vm = vf[0];
        #pragma unroll
        for (int c = 1; c < NC; ++c) vm = fmaxf(vm, vf[c]);
        float e[NC]; float wsum = 0.f;
        #pragma unroll
        for (int c = 0; c < NC; ++c) {
            float ex = __expf(vf[c] - vm);
            ex = (rank[c] < 5) ? ex : 0.f;
            e[c] = ex; wsum += ex;
        }
        const float inv = 1.f / wsum;
        #pragma unroll
        for (int k = 0; k < 5; ++k) {
            int idx = 0; float wv = 0.f;
            #pragma unroll
            for (int c = 0; c < NC; ++c) {
                const bool is = (rank[c] == k);
                idx += is ? cid[c] : 0;
                wv  += is ? e[c]  : 0.f;
            }
            selidx[t][k] = idx; selw[t][k] = wv * inv;
        }
    }
    __syncthreads();

    if (flagL[ql]) {
        double ssd = 0.0;
        #pragma unroll
        for (int j = 0; j < 16; ++j) ssd += (double)qf[j] * (double)qf[j];
        #pragma unroll
        for (int o = 1; o < 16; o <<= 1) ssd += __shfl_xor(ssd, o, 16);
        double nd = sqrt(ssd); if (nd < 1e-12) nd = 1e-12;
        const double qid = 1.0 / nd;
        double sd[NC];
        #pragma unroll
        for (int c = 0; c < NC; ++c) {
            const float* brow = bank + (size_t)ci[c] * DIM + u * 4;
            double a0 = 0, a1 = 0, a2 = 0, a3 = 0;
            #pragma unroll
            for (int j = 0; j < 4; ++j) {
                float4 b = *(const float4*)(brow + j * 64);
                a0 += (double)qf[j*4+0] * b.x; a1 += (double)qf[j*4+1] * b.y;
                a2 += (double)qf[j*4+2] * b.z; a3 += (double)qf[j*4+3] * b.w;
            }
            sd[c] = (a0 + a1) + (a2 + a3);
        }
        #pragma unroll
        for (int o = 1; o < 16; o <<= 1)
            #pragma unroll
            for (int c = 0; c < NC; ++c) sd[c] += __shfl_xor(sd[c], o, 16);
        #pragma unroll
        for (int c = 0; c < NC; ++c)
            if (u == c) simsD[ql * NC + c] = sd[c] * qid * bdD[ql * NC + c];
    }
    __syncthreads();

    if (t < 16 && flagL[t]) {
        double vd[NC];
        unsigned long long key[NC];
        int cid[NC];
        #pragma unroll
        for (int c = 0; c < NC; ++c) {
            cid[c] = cidxL[t * NC + c];
            double v = simsD[t * NC + c];
            vd[c] = v;
            unsigned long long ub = __builtin_bit_cast(unsigned long long, v);
            unsigned long long m = (ub >> 63) ? ~ub : (ub | 0x8000000000000000ULL);
            key[c] = (m & ~0x3FFULL) | (unsigned long long)(1023 - cid[c]);
        }
        int rank[NC];
        #pragma unroll
        for (int c = 0; c < NC; ++c) rank[c] = 0;
        #pragma unroll
        for (int c1 = 0; c1 < NC; ++c1)
            #pragma unroll
            for (int c2 = c1 + 1; c2 < NC; ++c2) {
                const bool gt = key[c1] > key[c2];
                rank[c2] += gt ? 1 : 0;
                rank[c1] += gt ? 0 : 1;
            }
        float vf[NC];
        #pragma unroll
        for (int c = 0; c < NC; ++c) vf[c] = (float)vd[c];
        float vm = vf[0];
        #pragma unroll
        for (int c = 1; c < NC; ++c) vm = fmaxf(vm, vf[c]);
        float e[NC]; float wsum = 0.f;
        #pragma unroll
        for (int c = 0; c < NC; ++c) {
            float ex = __expf(vf[c] - vm);
            ex = (rank[c] < 5) ? ex : 0.f;
            e[c] = ex; wsum += ex;
        }
        const float inv = 1.f / wsum;
        #pragma unroll
        for (int k = 0; k < 5; ++k) {
            int idx = 0; float wv = 0.f;
            #pragma unroll
            for (int c = 0; c < NC; ++c) {
                const bool is = (rank[c] == k);
                idx += is ? cid[c] : 0;
                wv  += is ? e[c]  : 0.f;
            }
            selidx[t][k] = idx; selw[t][k] = wv * inv;
        }
    }
    __syncthreads();

    float wk[5]; int ik[5];
    #pragma unroll
    for (int k = 0; k < 5; ++k) { wk[k] = selw[ql][k]; ik[k] = selidx[ql][k]; }
    float4 oa[4];
    #pragma unroll
    for (int j = 0; j < 4; ++j) { oa[j].x = 0.f; oa[j].y = 0.f; oa[j].z = 0.f; oa[j].w = 0.f; }
    #pragma unroll
    for (int k = 0; k < 5; ++k) {
        const float wc = wk[k];
        const float* brow = bank + (size_t)ik[k] * DIM + u * 4;
        #pragma unroll
        for (int j = 0; j < 4; ++j) {
            float4 b = *(const float4*)(brow + j * 64);
            oa[j].x += wc * b.x; oa[j].y += wc * b.y;
            oa[j].z += wc * b.z; oa[j].w += wc * b.w;
        }
    }
    short* od = nf + (size_t)q * DIM + u * 4;
    #pragma unroll
    for (int j = 0; j < 4; ++j) {
        uint2 pk;
        pk.x = ((unsigned)(unsigned short)f32bf(oa[j].x)) |
               (((unsigned)(unsigned short)f32bf(oa[j].y)) << 16);
        pk.y = ((unsigned)(unsigned short)f32bf(oa[j].z)) |
               (((unsigned)(unsigned short)f32bf(oa[j].w)) << 16);
        *(uint2*)(od + j * 64) = pk;
    }
}

// ---------------------------------------------------------- fused MLP v2 ----
// Weights NEVER touch LDS: B-fragments are loaded straight from global
// (0.4 MB, L2-resident, every block reads the same lines). A (feat|nf) is
// double-buffered in LDS -> ONE barrier per K-chunk; layer 2 reads Hs
// read-only -> zero per-chunk barriers. LDS 44 KB -> 3 blocks/CU.
__global__ __launch_bounds__(256, 4) void k_mlp(const float* __restrict__ feat,
        const short* __restrict__ nf, const short* __restrict__ w1bf,
        const short* __restrict__ w2bf, const float* __restrict__ b1,
        const float* __restrict__ b2, float* __restrict__ out)
{
    __shared__ alignas(16) short As[2][64 * 40];
    __shared__ alignas(16) short Hs[64 * 264];
    const int t = threadIdx.x, lane = t & 63, w = t >> 6;
    const int mb = blockIdx.x * 64;
    const int r = t >> 2, p = t & 3;
    const int n16 = lane & 15, ko = (lane >> 4) << 3;
    const int rq = (lane >> 4) << 2, cc = lane & 15;
    const f32x4 vzero = {0.f, 0.f, 0.f, 0.f};

    f32x4 acc[4][4];
    #pragma unroll
    for (int a = 0; a < 4; ++a)
        #pragma unroll
        for (int b = 0; b < 4; ++b) acc[a][b] = vzero;

    // stage chunk 0 (feat) into As[0]
    {
        const float4* s = (const float4*)(feat + (size_t)(mb + r) * 256 + p * 8);
        float4 v0 = s[0], v1 = s[1];
        short* ad = As[0] + r * 40 + p * 8;
        ad[0] = f32bf(v0.x); ad[1] = f32bf(v0.y); ad[2] = f32bf(v0.z); ad[3] = f32bf(v0.w);
        ad[4] = f32bf(v1.x); ad[5] = f32bf(v1.y); ad[6] = f32bf(v1.z); ad[7] = f32bf(v1.w);
    }
    __syncthreads();

    // ---- layer 1: 16 K-chunks, 1 barrier each ----
    for (int kc = 0; kc < 16; ++kc) {
        // prefetch chunk kc+1 into the other buffer
        if (kc < 15) {
            const int kn = kc + 1;
            short* ad = As[kn & 1] + r * 40 + p * 8;
            if (kn < 8) {
                const float4* s = (const float4*)(feat + (size_t)(mb + r) * 256 + kn * 32 + p * 8);
                float4 v0 = s[0], v1 = s[1];
                ad[0] = f32bf(v0.x); ad[1] = f32bf(v0.y); ad[2] = f32bf(v0.z); ad[3] = f32bf(v0.w);
                ad[4] = f32bf(v1.x); ad[5] = f32bf(v1.y); ad[6] = f32bf(v1.z); ad[7] = f32bf(v1.w);
            } else {
                *(uint4*)ad = *(const uint4*)(nf + (size_t)(mb + r) * 256 + (kn - 8) * 32 + p * 8);
            }
        }
        // B-fragments straight from global (L2-hot)
        short8 bf[4];
        #pragma unroll
        for (int nt = 0; nt < 4; ++nt)
            bf[nt] = *(const short8*)(w1bf + (size_t)(w * 64 + nt * 16 + n16) * 512 + kc * 32 + ko);
        short8 af[4];
        const short* cur = As[kc & 1];
        #pragma unroll
        for (int mt = 0; mt < 4; ++mt)
            af[mt] = *(const short8*)(cur + (mt * 16 + n16) * 40 + ko);
        #pragma unroll
        for (int mt = 0; mt < 4; ++mt)
            #pragma unroll
            for (int nt = 0; nt < 4; ++nt)
                acc[mt][nt] = __builtin_amdgcn_mfma_f32_16x16x32_bf16(af[mt], bf[nt], acc[mt][nt], 0, 0, 0);
        __syncthreads();
    }

    // epilogue 1: bias + relu -> Hs
    #pragma unroll
    for (int mt = 0; mt < 4; ++mt)
        #pragma unroll
        for (int nt = 0; nt < 4; ++nt) {
            const int row = mt * 16 + rq;
            const int col = w * 64 + nt * 16 + cc;
            const float bias = b1[col];
            #pragma unroll
            for (int rr = 0; rr < 4; ++rr) {
                float v = acc[mt][nt][rr] + bias;
                Hs[(row + rr) * 264 + col] = f32bf(fmaxf(v, 0.f));
            }
        }
    #pragma unroll
    for (int a = 0; a < 4; ++a)
        #pragma unroll
        for (int b = 0; b < 4; ++b) acc[a][b] = vzero;
    __syncthreads();

    // ---- layer 2: barrier-free K-loop (Hs read-only, weights global) ----
    for (int kc = 0; kc < 8; ++kc) {
        short8 bf[4];
        #pragma unroll
        for (int nt = 0; nt < 4; ++nt)
            bf[nt] = *(const short8*)(w2bf + (size_t)(w * 64 + nt * 16 + n16) * 256 + kc * 32 + ko);
        short8 af[4];
        #pragma unroll
        for (int mt = 0; mt < 4; ++mt)
            af[mt] = *(const short8*)(Hs + (mt * 16 + n16) * 264 + kc * 32 + ko);
        #pragma unroll
        for (int mt = 0; mt < 4; ++mt)
            #pragma unroll
            for (int nt = 0; nt < 4; ++nt)
                acc[mt][nt] = __builtin_amdgcn_mfma_f32_16x16x32_bf16(af[mt], bf[nt], acc[mt][nt], 0, 0, 0);
    }
    #pragma unroll
    for (int mt = 0; mt < 4; ++mt)
        #pragma unroll
        for (int nt = 0; nt < 4; ++nt) {
            const int row = mb + mt * 16 + rq;
            const int col = w * 64 + nt * 16 + cc;
            const float bias = b2[col];
            #pragma unroll
            for (int rr = 0; rr < 4; ++rr)
                out[(size_t)(row + rr) * 256 + col] = acc[mt][nt][rr] + bias;
        }
}

// ------------------------------------------------------------- launcher -----
extern "C" void kernel_launch(void* const* d_in, const int* in_sizes, int n_in,
                              void* d_out, int out_size, void* d_ws, size_t ws_size,
                              hipStream_t stream) {
    const float* feat = (const float*)d_in[0];
    const float* bank = (const float*)d_in[1];
    const float* W1   = (const float*)d_in[2];
    const float* b1   = (const float*)d_in[3];
    const float* W2   = (const float*)d_in[4];
    const float* b2   = (const float*)d_in[5];
    float* out = (float*)d_out;

    char* ws = (char*)d_ws;
    short*  bnbf = (short*)(ws + 0);              // 1024*256*2   = 524288
    double* binv = (double*)(ws + 524288);        // 1024*8       = 8192
    short*  w1bf = (short*)(ws + 532480);         // 131072*2     = 262144
    short*  w2bf = (short*)(ws + 794624);         // 65536*2      = 131072
    int*    top  = (int*)(ws + 925696);           // 65536*12*4   = 3145728
    short*  nf   = (short*)(ws + 4071424);        // 65536*256*2  = 33554432
    short*  X    = (short*)(ws + 37625856);       // 33554432: sims slices
    // total 71180288 bytes

    k_prep<<<1792, 256, 0, stream>>>(bank, W1, W2, bnbf, binv, w1bf, w2bf);
    for (int s = 0; s < 4; ++s) {
        const int qoff = s * 16384;
        k_sims  <<<512,  256, 0, stream>>>(feat, bnbf, X, qoff);
        k_select<<<4096, 256, 0, stream>>>(X, top, qoff);
    }
    k_refine<<<4096, 256, 0, stream>>>(feat, bank, top, binv, nf);
    k_mlp   <<<1024, 256, 0, stream>>>(feat, nf, w1bf, w2bf, b1, b2, out);
}